// Round 1
// baseline (581.851 us; speedup 1.0000x reference)
//
#include <hip/hip_runtime.h>

// SCAM fused kernel for MI355X (gfx950) — v2 "occupancy" restructure.
// One block per (b,h) slice (1024 blocks), 512 threads = 8 waves, each wave
// owns a 16-row band. Single 32 KB LDS slot, time-shared across phases.
// Weights read as MFMA B-fragments directly from global (128 KB, L1/L2-hot).
// x loaded directly in A-fragment layout (no LDS staging); PV fused into
// the global epilogue (no f staging).

typedef __attribute__((ext_vector_type(8))) __bf16 bf16x8;
typedef __attribute__((ext_vector_type(4))) __bf16 bf16x4;
typedef __attribute__((ext_vector_type(4))) float f4;

#define MFMA(A, B, C) __builtin_amdgcn_mfma_f32_16x16x32_bf16((A), (B), (C), 0, 0, 0)
#define SCALE_QK 0.08838834764831845f  // 128^-0.5

// XOR-swizzled LDS offset for a [128][128] bf16 slot (256 B row stride).
static __device__ __forceinline__ int eoff(int n, int k) {
  return (n << 8) + ((((k >> 3) ^ (n & 7)) << 4) | ((k & 7) << 1));
}

// Prep: transpose 4 fp32 [k][n] weight matrices to bf16 [n][k] in workspace.
__global__ void prep_w(const float* __restrict__ w0, const float* __restrict__ w1,
                       const float* __restrict__ w2, const float* __restrict__ w3,
                       __bf16* __restrict__ out) {
  int m = blockIdx.y;
  const float* src = (m == 0) ? w0 : (m == 1) ? w1 : (m == 2) ? w2 : w3;
  int t = blockIdx.x * 256 + threadIdx.x;  // 0..16383
  int k = t >> 7, n = t & 127;
  out[m * 16384 + n * 128 + k] = (__bf16)src[k * 128 + n];
}

// Load one row's 32 elements (A-fragment layout: row = w*16+l16,
// k = ks*32 + quad*8 + 0..7), compute LayerNorm over the row (2 shfls),
// emit raw-x and ln(x) bf16 A-fragments. No LDS.
static __device__ __forceinline__ void ln_side(const float* __restrict__ xp, size_t base,
                                               const float* __restrict__ g,
                                               const float* __restrict__ b, int row,
                                               int quad, bf16x8* xF, bf16x8* lF) {
  float4 v[8];
#pragma unroll
  for (int t = 0; t < 8; ++t)
    v[t] = *(const float4*)(xp + base + row * 128 + (t >> 1) * 32 + quad * 8 + (t & 1) * 4);
  float s = 0.f, s2 = 0.f;
#pragma unroll
  for (int t = 0; t < 8; ++t) {
    s += v[t].x + v[t].y + v[t].z + v[t].w;
    s2 += v[t].x * v[t].x + v[t].y * v[t].y + v[t].z * v[t].z + v[t].w * v[t].w;
  }
  // row is shared by the 4 quads (lane bits 4,5) -> 2-step reduce
  s += __shfl_xor(s, 16);
  s += __shfl_xor(s, 32);
  s2 += __shfl_xor(s2, 16);
  s2 += __shfl_xor(s2, 32);
  float mean = s * 0.0078125f;
  float var = s2 * 0.0078125f - mean * mean;
  float rstd = rsqrtf(var + 1e-6f);
#pragma unroll
  for (int ks = 0; ks < 4; ++ks) {
    bf16x8 xu, lu;
#pragma unroll
    for (int t = 0; t < 2; ++t) {
      float4 q = v[ks * 2 + t];
      float4 gv = *(const float4*)(g + ks * 32 + quad * 8 + t * 4);
      float4 bv = *(const float4*)(b + ks * 32 + quad * 8 + t * 4);
      xu[t * 4 + 0] = (__bf16)q.x;
      xu[t * 4 + 1] = (__bf16)q.y;
      xu[t * 4 + 2] = (__bf16)q.z;
      xu[t * 4 + 3] = (__bf16)q.w;
      lu[t * 4 + 0] = (__bf16)((q.x - mean) * rstd * gv.x + bv.x);
      lu[t * 4 + 1] = (__bf16)((q.y - mean) * rstd * gv.y + bv.y);
      lu[t * 4 + 2] = (__bf16)((q.z - mean) * rstd * gv.z + bv.z);
      lu[t * 4 + 3] = (__bf16)((q.w - mean) * rstd * gv.w + bv.w);
    }
    xF[ks] = xu;
    lF[ks] = lu;
  }
}

// Projection: out = A @ W + bias. A from registers, W B-fragments straight
// from global (bf16 [n][k], L1/L2-hot: 32 KB reused by all 1024 blocks).
// TRANSPOSED=0: row-major [i][c] into slot. TRANSPOSED=1: [c][i] (for V^T).
template <int TRANSPOSED>
static __device__ __forceinline__ void proj_g(const bf16x8* aF,
                                              const __bf16* __restrict__ wTm, char* dst,
                                              const float* __restrict__ bias, float scale,
                                              int w, int l16, int quad) {
#pragma unroll
  for (int nt = 0; nt < 8; ++nt) {
    f4 a = {0.f, 0.f, 0.f, 0.f};
    const __bf16* wrow = wTm + (nt * 16 + l16) * 128 + quad * 8;
#pragma unroll
    for (int ks = 0; ks < 4; ++ks) {
      bf16x8 bf = *(const bf16x8*)(wrow + ks * 32);
      a = MFMA(aF[ks], bf, a);
    }
    float bs = bias[nt * 16 + l16];
    if (TRANSPOSED) {
      int c = nt * 16 + l16;
      bf16x4 u;
#pragma unroll
      for (int r = 0; r < 4; ++r) u[r] = (__bf16)((a[r] + bs) * scale);
      *(bf16x4*)(dst + eoff(c, w * 16 + quad * 4)) = u;
    } else {
#pragma unroll
      for (int r = 0; r < 4; ++r) {
        int i = w * 16 + quad * 4 + r;
        *(__bf16*)(dst + eoff(i, nt * 16 + l16)) = (__bf16)((a[r] + bs) * scale);
      }
    }
  }
}

// f = P @ V fused with epilogue: out = x + scl[c] * f, straight to global.
static __device__ __forceinline__ void pv_epi(const bf16x8* pF, const char* vslot,
                                              const float* __restrict__ xp, size_t base,
                                              const float* __restrict__ scl,
                                              float* __restrict__ outp, int w, int l16,
                                              int quad) {
#pragma unroll
  for (int nt = 0; nt < 8; ++nt) {
    f4 a = {0.f, 0.f, 0.f, 0.f};
#pragma unroll
    for (int ks = 0; ks < 4; ++ks) {
      bf16x8 bf = *(const bf16x8*)(vslot + eoff(nt * 16 + l16, ks * 32 + quad * 8));
      a = MFMA(pF[ks], bf, a);
    }
    int c = nt * 16 + l16;
    float sv = scl[c];
#pragma unroll
    for (int r = 0; r < 4; ++r) {
      int i = w * 16 + quad * 4 + r;
      outp[base + i * 128 + c] = xp[base + i * 128 + c] + sv * (float)a[r];
    }
  }
}

__global__ __launch_bounds__(512, 4) void scam_fused(
    const float* __restrict__ xl, const float* __restrict__ xr,
    const float* __restrict__ gl, const float* __restrict__ bl,
    const float* __restrict__ gr, const float* __restrict__ br,
    const __bf16* __restrict__ wT,  // 4 x [128][128] bf16, order: ql, qr, vl, vr
    const float* __restrict__ bql, const float* __restrict__ bqr,
    const float* __restrict__ bvl, const float* __restrict__ bvr,
    const float* __restrict__ beta, const float* __restrict__ gamma,
    float* __restrict__ out0, float* __restrict__ out1) {
  __shared__ char S[32768];  // single time-shared 128x128 bf16 slot
  int tid = threadIdx.x;
  int lane = tid & 63, w = tid >> 6;  // 8 waves, wave w owns rows [16w,16w+16)
  int quad = lane >> 4, l16 = lane & 15;
  int row = w * 16 + l16;
  size_t base = (size_t)blockIdx.x << 14;  // bh * 128*128

  // ---- Phase A: LayerNorm both sides straight into register A-fragments ----
  bf16x8 xlF[4], llF[4], xrF[4], lrF[4];
  ln_side(xl, base, gl, bl, row, quad, xlF, llF);
  ln_side(xr, base, gr, br, row, quad, xrF, lrF);

  // ---- Phase B: q_l = (ln_l @ Wql + b) * SCALE -> slot -> A-frags ----
  proj_g<0>(llF, wT, S, bql, SCALE_QK, w, l16, quad);
  __syncthreads();
  bf16x8 qlF[4];
#pragma unroll
  for (int ks = 0; ks < 4; ++ks)
    qlF[ks] = *(const bf16x8*)(S + eoff(row, ks * 32 + quad * 8));
  __syncthreads();

  // ---- Phase C: q_r = ln_r @ Wqr + b -> slot (row-major [j][c]) ----
  proj_g<0>(lrF, wT + 16384, S, bqr, 1.0f, w, l16, quad);
  __syncthreads();

  // ---- Phase D: S = q_l @ q_r^T ----
  f4 sacc[8];
#pragma unroll
  for (int nt = 0; nt < 8; ++nt) {
    f4 z = {0.f, 0.f, 0.f, 0.f};
    sacc[nt] = z;
  }
#pragma unroll
  for (int nt = 0; nt < 8; ++nt)
#pragma unroll
    for (int ks = 0; ks < 4; ++ks) {
      bf16x8 bf = *(const bf16x8*)(S + eoff(nt * 16 + l16, ks * 32 + quad * 8));
      sacc[nt] = MFMA(qlF[ks], bf, sacc[nt]);
    }

  // ---- Phase E: dual softmax stats ----
  // Row stats: row i = w*16+quad*4+r spans the 16 l16-lanes of one quad.
  float rm[4], rinv[4];
#pragma unroll
  for (int r = 0; r < 4; ++r) {
    float m = -1e30f;
#pragma unroll
    for (int nt = 0; nt < 8; ++nt) m = fmaxf(m, sacc[nt][r]);
#pragma unroll
    for (int d = 1; d < 16; d <<= 1) m = fmaxf(m, __shfl_xor(m, d));
    float s = 0.f;
#pragma unroll
    for (int nt = 0; nt < 8; ++nt) s += __expf(sacc[nt][r] - m);
#pragma unroll
    for (int d = 1; d < 16; d <<= 1) s += __shfl_xor(s, d);
    rm[r] = m;
    rinv[r] = 1.f / s;
  }
  // Col stats: quad shuffles, then cross-wave via scratch overlaid on slot.
  float* colred0 = (float*)S;             // 8 waves x 128 cols = 4 KB
  float* colred1 = (float*)(S + 4096);    // second 4 KB region
  float cm[8], cinv[8];
#pragma unroll
  for (int nt = 0; nt < 8; ++nt) {
    float m = fmaxf(fmaxf(sacc[nt][0], sacc[nt][1]), fmaxf(sacc[nt][2], sacc[nt][3]));
    m = fmaxf(m, __shfl_xor(m, 16));
    m = fmaxf(m, __shfl_xor(m, 32));
    cm[nt] = m;
  }
  __syncthreads();  // all waves done reading q_r from slot
  if (quad == 0) {
#pragma unroll
    for (int nt = 0; nt < 8; ++nt) colred0[w * 128 + nt * 16 + l16] = cm[nt];
  }
  __syncthreads();
#pragma unroll
  for (int nt = 0; nt < 8; ++nt) {
    float m = cm[nt];
#pragma unroll
    for (int ww = 0; ww < 8; ++ww) m = fmaxf(m, colred0[ww * 128 + nt * 16 + l16]);
    cm[nt] = m;
  }
#pragma unroll
  for (int nt = 0; nt < 8; ++nt) {
    float s = __expf(sacc[nt][0] - cm[nt]) + __expf(sacc[nt][1] - cm[nt]) +
              __expf(sacc[nt][2] - cm[nt]) + __expf(sacc[nt][3] - cm[nt]);
    s += __shfl_xor(s, 16);
    s += __shfl_xor(s, 32);
    cinv[nt] = s;  // wave-local column sum
  }
  if (quad == 0) {
#pragma unroll
    for (int nt = 0; nt < 8; ++nt) colred1[w * 128 + nt * 16 + l16] = cinv[nt];
  }
  __syncthreads();
#pragma unroll
  for (int nt = 0; nt < 8; ++nt) {
    float s = 0.f;
#pragma unroll
    for (int ww = 0; ww < 8; ++ww) s += colred1[ww * 128 + nt * 16 + l16];
    cinv[nt] = 1.f / s;
  }
  __syncthreads();  // colred consumed; slot free

  // ---- Phase F: P_r (row-softmax) -> slot; P_c kept packed in registers ----
  bf16x4 pcPack[8];
#pragma unroll
  for (int nt = 0; nt < 8; ++nt) {
    bf16x4 pc;
#pragma unroll
    for (int r = 0; r < 4; ++r) {
      float sv = sacc[nt][r];
      int i = w * 16 + quad * 4 + r;
      *(__bf16*)(S + eoff(i, nt * 16 + l16)) = (__bf16)(__expf(sv - rm[r]) * rinv[r]);
      pc[r] = (__bf16)(__expf(sv - cm[nt]) * cinv[nt]);
    }
    pcPack[nt] = pc;
  }
  __syncthreads();
  bf16x8 prF[4];
#pragma unroll
  for (int ks = 0; ks < 4; ++ks)
    prF[ks] = *(const bf16x8*)(S + eoff(row, ks * 32 + quad * 8));
  __syncthreads();

  // ---- Phase G/H: v_r^T -> slot, f_r2l fused epilogue -> out0 ----
  proj_g<1>(xrF, wT + 3 * 16384, S, bvr, 1.0f, w, l16, quad);
  __syncthreads();
  pv_epi(prF, S, xl, base, beta, out0, w, l16, quad);
  __syncthreads();

  // ---- Phase I: P_c^T -> slot -> A-frags ----
#pragma unroll
  for (int nt = 0; nt < 8; ++nt)
    *(bf16x4*)(S + eoff(nt * 16 + l16, w * 16 + quad * 4)) = pcPack[nt];
  __syncthreads();
  bf16x8 pcF[4];
#pragma unroll
  for (int ks = 0; ks < 4; ++ks)
    pcF[ks] = *(const bf16x8*)(S + eoff(row, ks * 32 + quad * 8));
  __syncthreads();

  // ---- Phase J/K: v_l^T -> slot, f_l2r fused epilogue -> out1 ----
  proj_g<1>(xlF, wT + 2 * 16384, S, bvl, 1.0f, w, l16, quad);
  __syncthreads();
  pv_epi(pcF, S, xr, base, gamma, out1, w, l16, quad);
}

extern "C" void kernel_launch(void* const* d_in, const int* in_sizes, int n_in,
                              void* d_out, int out_size, void* d_ws, size_t ws_size,
                              hipStream_t stream) {
  const float* xl = (const float*)d_in[0];
  const float* xr = (const float*)d_in[1];
  const float* gl = (const float*)d_in[2];
  const float* bl = (const float*)d_in[3];
  const float* gr = (const float*)d_in[4];
  const float* br = (const float*)d_in[5];
  const float* wql = (const float*)d_in[6];
  const float* bql = (const float*)d_in[7];
  const float* wqr = (const float*)d_in[8];
  const float* bqr = (const float*)d_in[9];
  const float* wvl = (const float*)d_in[10];
  const float* bvl = (const float*)d_in[11];
  const float* wvr = (const float*)d_in[12];
  const float* bvr = (const float*)d_in[13];
  const float* beta = (const float*)d_in[14];
  const float* gamma = (const float*)d_in[15];

  __bf16* wT = (__bf16*)d_ws;          // 4 * 16384 bf16 = 128 KB scratch
  float* out0 = (float*)d_out;         // [8,128,128,128] fp32
  float* out1 = out0 + (size_t)8 * 128 * 128 * 128;

  prep_w<<<dim3(64, 4), 256, 0, stream>>>(wql, wqr, wvl, wvr, wT);
  scam_fused<<<1024, 512, 0, stream>>>(xl, xr, gl, bl, gr, br, wT, bql, bqr, bvl, bvr,
                                       beta, gamma, out0, out1);
}

// Round 2
// 460.356 us; speedup vs baseline: 1.2639x; 1.2639x over previous
//
#include <hip/hip_runtime.h>

// SCAM fused kernel for MI355X (gfx950) — v3 "no-spill" restructure.
// 1024 blocks (one per (b,h) slice), 512 threads = 8 waves, wave owns a
// 16-row band. Two 32 KB LDS slots + 8 KB colred scratch (72 KB, 2 blocks/CU).
// Register budget kept under the 128-reg cap of __launch_bounds__(512,4):
// ln-frags die after the Q projections; raw-x fragments are re-materialized
// from global (L3-resident) right before the V projections; P_c^T lives in
// LDS, not registers. 6 barriers total.

typedef __attribute__((ext_vector_type(8))) __bf16 bf16x8;
typedef __attribute__((ext_vector_type(4))) __bf16 bf16x4;
typedef __attribute__((ext_vector_type(4))) float f4;

#define MFMA(A, B, C) __builtin_amdgcn_mfma_f32_16x16x32_bf16((A), (B), (C), 0, 0, 0)
#define SCALE_QK 0.08838834764831845f  // 128^-0.5

// XOR-swizzled LDS offset for a [128][128] bf16 slot (256 B row stride).
static __device__ __forceinline__ int eoff(int n, int k) {
  return (n << 8) + ((((k >> 3) ^ (n & 7)) << 4) | ((k & 7) << 1));
}

// Prep: transpose 4 fp32 [k][n] weight matrices to bf16 [n][k] in workspace.
__global__ void prep_w(const float* __restrict__ w0, const float* __restrict__ w1,
                       const float* __restrict__ w2, const float* __restrict__ w3,
                       __bf16* __restrict__ out) {
  int m = blockIdx.y;
  const float* src = (m == 0) ? w0 : (m == 1) ? w1 : (m == 2) ? w2 : w3;
  int t = blockIdx.x * 256 + threadIdx.x;  // 0..16383
  int k = t >> 7, n = t & 127;
  out[m * 16384 + n * 128 + k] = (__bf16)src[k * 128 + n];
}

// LayerNorm of one row (A-frag layout: row = w*16+l16, k = ks*32+quad*8+0..7),
// row reduce = 2 shuffles (row shared by 4 quads). Emits ln(x) bf16 A-frags.
static __device__ __forceinline__ void ln_frags(const float* __restrict__ xp, size_t base,
                                                const float* __restrict__ g,
                                                const float* __restrict__ b, int row,
                                                int quad, bf16x8* lF) {
  float4 v[8];
#pragma unroll
  for (int t = 0; t < 8; ++t)
    v[t] = *(const float4*)(xp + base + row * 128 + (t >> 1) * 32 + quad * 8 + (t & 1) * 4);
  float s = 0.f, s2 = 0.f;
#pragma unroll
  for (int t = 0; t < 8; ++t) {
    s += v[t].x + v[t].y + v[t].z + v[t].w;
    s2 += v[t].x * v[t].x + v[t].y * v[t].y + v[t].z * v[t].z + v[t].w * v[t].w;
  }
  s += __shfl_xor(s, 16);
  s += __shfl_xor(s, 32);
  s2 += __shfl_xor(s2, 16);
  s2 += __shfl_xor(s2, 32);
  float mean = s * 0.0078125f;
  float var = s2 * 0.0078125f - mean * mean;
  float rstd = rsqrtf(var + 1e-6f);
#pragma unroll
  for (int ks = 0; ks < 4; ++ks) {
    bf16x8 lu;
#pragma unroll
    for (int t = 0; t < 2; ++t) {
      float4 q = v[ks * 2 + t];
      float4 gv = *(const float4*)(g + ks * 32 + quad * 8 + t * 4);
      float4 bv = *(const float4*)(b + ks * 32 + quad * 8 + t * 4);
      lu[t * 4 + 0] = (__bf16)((q.x - mean) * rstd * gv.x + bv.x);
      lu[t * 4 + 1] = (__bf16)((q.y - mean) * rstd * gv.y + bv.y);
      lu[t * 4 + 2] = (__bf16)((q.z - mean) * rstd * gv.z + bv.z);
      lu[t * 4 + 3] = (__bf16)((q.w - mean) * rstd * gv.w + bv.w);
    }
    lF[ks] = lu;
  }
}

// Raw x row -> bf16 A-frags (re-materialization read; x is L3-resident).
static __device__ __forceinline__ void x_frags(const float* __restrict__ xp, size_t base,
                                               int row, int quad, bf16x8* xF) {
#pragma unroll
  for (int ks = 0; ks < 4; ++ks) {
    bf16x8 xu;
#pragma unroll
    for (int t = 0; t < 2; ++t) {
      float4 q = *(const float4*)(xp + base + row * 128 + ks * 32 + quad * 8 + t * 4);
      xu[t * 4 + 0] = (__bf16)q.x;
      xu[t * 4 + 1] = (__bf16)q.y;
      xu[t * 4 + 2] = (__bf16)q.z;
      xu[t * 4 + 3] = (__bf16)q.w;
    }
    xF[ks] = xu;
  }
}

// Projection: out = A @ W + bias. A from registers, W B-fragments straight
// from global (bf16 [n][k], L1/L2-hot: 32 KB reused by all 1024 blocks).
// TRANSPOSED=0: row-major [i][c] into slot. TRANSPOSED=1: [c][i] (for V^T).
template <int TRANSPOSED>
static __device__ __forceinline__ void proj_g(const bf16x8* aF,
                                              const __bf16* __restrict__ wTm, char* dst,
                                              const float* __restrict__ bias, float scale,
                                              int w, int l16, int quad) {
#pragma unroll
  for (int nt = 0; nt < 8; ++nt) {
    f4 a = {0.f, 0.f, 0.f, 0.f};
    const __bf16* wrow = wTm + (nt * 16 + l16) * 128 + quad * 8;
#pragma unroll
    for (int ks = 0; ks < 4; ++ks) {
      bf16x8 bf = *(const bf16x8*)(wrow + ks * 32);
      a = MFMA(aF[ks], bf, a);
    }
    float bs = bias[nt * 16 + l16];
    if (TRANSPOSED) {
      int c = nt * 16 + l16;
      bf16x4 u;
#pragma unroll
      for (int r = 0; r < 4; ++r) u[r] = (__bf16)((a[r] + bs) * scale);
      *(bf16x4*)(dst + eoff(c, w * 16 + quad * 4)) = u;
    } else {
#pragma unroll
      for (int r = 0; r < 4; ++r) {
        int i = w * 16 + quad * 4 + r;
        *(__bf16*)(dst + eoff(i, nt * 16 + l16)) = (__bf16)((a[r] + bs) * scale);
      }
    }
  }
}

// f = P @ V fused with epilogue: out = x + scl[c] * f, straight to global.
static __device__ __forceinline__ void pv_epi(const bf16x8* pF, const char* vslot,
                                              const float* __restrict__ xp, size_t base,
                                              const float* __restrict__ scl,
                                              float* __restrict__ outp, int w, int l16,
                                              int quad) {
#pragma unroll
  for (int nt = 0; nt < 8; ++nt) {
    f4 a = {0.f, 0.f, 0.f, 0.f};
#pragma unroll
    for (int ks = 0; ks < 4; ++ks) {
      bf16x8 bf = *(const bf16x8*)(vslot + eoff(nt * 16 + l16, ks * 32 + quad * 8));
      a = MFMA(pF[ks], bf, a);
    }
    int c = nt * 16 + l16;
    float sv = scl[c];
#pragma unroll
    for (int r = 0; r < 4; ++r) {
      int i = w * 16 + quad * 4 + r;
      outp[base + i * 128 + c] = xp[base + i * 128 + c] + sv * (float)a[r];
    }
  }
}

__global__ __launch_bounds__(512, 4) void scam_fused(
    const float* __restrict__ xl, const float* __restrict__ xr,
    const float* __restrict__ gl, const float* __restrict__ bl,
    const float* __restrict__ gr, const float* __restrict__ br,
    const __bf16* __restrict__ wT,  // 4 x [128][128] bf16, order: ql, qr, vl, vr
    const float* __restrict__ bql, const float* __restrict__ bqr,
    const float* __restrict__ bvl, const float* __restrict__ bvr,
    const float* __restrict__ beta, const float* __restrict__ gamma,
    float* __restrict__ out0, float* __restrict__ out1) {
  __shared__ char S[73728];       // S1 32K | S2 32K | colred 8K
  char* S1 = S;
  char* S2 = S + 32768;
  float* colred0 = (float*)(S + 65536);  // 8 waves x 128 cols
  float* colred1 = (float*)(S + 69632);
  int tid = threadIdx.x;
  int lane = tid & 63, w = tid >> 6;  // wave w owns rows [16w, 16w+16)
  int quad = lane >> 4, l16 = lane & 15;
  int row = w * 16 + l16;
  size_t base = (size_t)blockIdx.x << 14;  // bh * 128*128

  // ---- Phase A: LayerNorm both sides -> register A-fragments (ln only) ----
  bf16x8 llF[4], lrF[4];
  ln_frags(xl, base, gl, bl, row, quad, llF);
  ln_frags(xr, base, gr, br, row, quad, lrF);

  // ---- Phase B: q_l*SCALE -> S1, q_r -> S2 (back-to-back MFMA runs) ----
  proj_g<0>(llF, wT, S1, bql, SCALE_QK, w, l16, quad);          // llF dies here
  proj_g<0>(lrF, wT + 16384, S2, bqr, 1.0f, w, l16, quad);      // lrF dies here
  __syncthreads();  // (1) q_r visible to all waves

  bf16x8 qlF[4];
#pragma unroll
  for (int ks = 0; ks < 4; ++ks)
    qlF[ks] = *(const bf16x8*)(S1 + eoff(row, ks * 32 + quad * 8));  // own band

  // ---- Phase D: S = q_l @ q_r^T ----
  f4 sacc[8];
#pragma unroll
  for (int nt = 0; nt < 8; ++nt) {
    f4 z = {0.f, 0.f, 0.f, 0.f};
    sacc[nt] = z;
  }
#pragma unroll
  for (int nt = 0; nt < 8; ++nt)
#pragma unroll
    for (int ks = 0; ks < 4; ++ks) {
      bf16x8 bf = *(const bf16x8*)(S2 + eoff(nt * 16 + l16, ks * 32 + quad * 8));
      sacc[nt] = MFMA(qlF[ks], bf, sacc[nt]);
    }

  // ---- Phase E: dual softmax stats ----
  // Row stats: row i = w*16+quad*4+r spans the 16 l16-lanes of one quad.
  float rm[4], rinv[4];
#pragma unroll
  for (int r = 0; r < 4; ++r) {
    float m = -1e30f;
#pragma unroll
    for (int nt = 0; nt < 8; ++nt) m = fmaxf(m, sacc[nt][r]);
#pragma unroll
    for (int d = 1; d < 16; d <<= 1) m = fmaxf(m, __shfl_xor(m, d));
    float s = 0.f;
#pragma unroll
    for (int nt = 0; nt < 8; ++nt) s += __expf(sacc[nt][r] - m);
#pragma unroll
    for (int d = 1; d < 16; d <<= 1) s += __shfl_xor(s, d);
    rm[r] = m;
    rinv[r] = 1.f / s;
  }
  // Col stats: quad shuffles then cross-wave via the dedicated colred region.
  float cm[8], cinv[8];
#pragma unroll
  for (int nt = 0; nt < 8; ++nt) {
    float m = fmaxf(fmaxf(sacc[nt][0], sacc[nt][1]), fmaxf(sacc[nt][2], sacc[nt][3]));
    m = fmaxf(m, __shfl_xor(m, 16));
    m = fmaxf(m, __shfl_xor(m, 32));
    cm[nt] = m;
  }
  if (quad == 0) {
#pragma unroll
    for (int nt = 0; nt < 8; ++nt) colred0[w * 128 + nt * 16 + l16] = cm[nt];
  }
  __syncthreads();  // (2) also orders: all waves are past Phase D reads
#pragma unroll
  for (int nt = 0; nt < 8; ++nt) {
    float m = cm[nt];
#pragma unroll
    for (int ww = 0; ww < 8; ++ww) m = fmaxf(m, colred0[ww * 128 + nt * 16 + l16]);
    cm[nt] = m;
  }
#pragma unroll
  for (int nt = 0; nt < 8; ++nt) {
    float s = __expf(sacc[nt][0] - cm[nt]) + __expf(sacc[nt][1] - cm[nt]) +
              __expf(sacc[nt][2] - cm[nt]) + __expf(sacc[nt][3] - cm[nt]);
    s += __shfl_xor(s, 16);
    s += __shfl_xor(s, 32);
    cinv[nt] = s;  // wave-local column sum
  }
  if (quad == 0) {
#pragma unroll
    for (int nt = 0; nt < 8; ++nt) colred1[w * 128 + nt * 16 + l16] = cinv[nt];
  }
  __syncthreads();  // (3)
#pragma unroll
  for (int nt = 0; nt < 8; ++nt) {
    float s = 0.f;
#pragma unroll
    for (int ww = 0; ww < 8; ++ww) s += colred1[ww * 128 + nt * 16 + l16];
    cinv[nt] = 1.f / s;
  }

  // ---- Phase F: P_r -> S1 (own band), P_c^T -> S2; sacc dies here ----
#pragma unroll
  for (int nt = 0; nt < 8; ++nt) {
    bf16x4 pc;
#pragma unroll
    for (int r = 0; r < 4; ++r) {
      float sv = sacc[nt][r];
      int i = w * 16 + quad * 4 + r;
      *(__bf16*)(S1 + eoff(i, nt * 16 + l16)) = (__bf16)(__expf(sv - rm[r]) * rinv[r]);
      pc[r] = (__bf16)(__expf(sv - cm[nt]) * cinv[nt]);
    }
    *(bf16x4*)(S2 + eoff(nt * 16 + l16, w * 16 + quad * 4)) = pc;
  }

  // Re-materialize raw-x fragments (x is L3-resident; loads overlap barrier).
  bf16x8 xlF[4], xrF[4];
  x_frags(xr, base, row, quad, xrF);
  x_frags(xl, base, row, quad, xlF);
  __syncthreads();  // (4) P tiles visible

  bf16x8 prF[4], pcF[4];
#pragma unroll
  for (int ks = 0; ks < 4; ++ks) {
    prF[ks] = *(const bf16x8*)(S1 + eoff(row, ks * 32 + quad * 8));
    pcF[ks] = *(const bf16x8*)(S2 + eoff(row, ks * 32 + quad * 8));
  }
  __syncthreads();  // (5) all P loads done before V^T overwrites slots

  // ---- Phase G: V_r^T -> S1, V_l^T -> S2 (back-to-back MFMA runs) ----
  proj_g<1>(xrF, wT + 3 * 16384, S1, bvr, 1.0f, w, l16, quad);
  proj_g<1>(xlF, wT + 2 * 16384, S2, bvl, 1.0f, w, l16, quad);
  __syncthreads();  // (6)

  // ---- Phase H: both PV matmuls fused with epilogues ----
  pv_epi(prF, S1, xl, base, beta, out0, w, l16, quad);
  pv_epi(pcF, S2, xr, base, gamma, out1, w, l16, quad);
}

extern "C" void kernel_launch(void* const* d_in, const int* in_sizes, int n_in,
                              void* d_out, int out_size, void* d_ws, size_t ws_size,
                              hipStream_t stream) {
  const float* xl = (const float*)d_in[0];
  const float* xr = (const float*)d_in[1];
  const float* gl = (const float*)d_in[2];
  const float* bl = (const float*)d_in[3];
  const float* gr = (const float*)d_in[4];
  const float* br = (const float*)d_in[5];
  const float* wql = (const float*)d_in[6];
  const float* bql = (const float*)d_in[7];
  const float* wqr = (const float*)d_in[8];
  const float* bqr = (const float*)d_in[9];
  const float* wvl = (const float*)d_in[10];
  const float* bvl = (const float*)d_in[11];
  const float* wvr = (const float*)d_in[12];
  const float* bvr = (const float*)d_in[13];
  const float* beta = (const float*)d_in[14];
  const float* gamma = (const float*)d_in[15];

  __bf16* wT = (__bf16*)d_ws;          // 4 * 16384 bf16 = 128 KB scratch
  float* out0 = (float*)d_out;         // [8,128,128,128] fp32
  float* out1 = out0 + (size_t)8 * 128 * 128 * 128;

  prep_w<<<dim3(64, 4), 256, 0, stream>>>(wql, wqr, wvl, wvr, wT);
  scam_fused<<<1024, 512, 0, stream>>>(xl, xr, gl, bl, gr, br, wT, bql, bqr, bvl, bvr,
                                       beta, gamma, out0, out1);
}

// Round 3
// 390.070 us; speedup vs baseline: 1.4917x; 1.1802x over previous
//
#include <hip/hip_runtime.h>

// SCAM fused kernel for MI355X (gfx950) — v4 "spill-free" tuning of v3.
// Same structure as v3 (1024 blocks, 8 waves x 16-row bands, two 32 KB LDS
// slots + 8 KB colred). Register-pressure fixes:
//  - #pragma unroll 2 on address-only nt-loops (proj_g / pv_epi) so the
//    scheduler can't hoist 32 in-flight loads at once (the v3 spill source).
//  - fragment lifetimes staggered: ln_r built after q_l's projection;
//    xrF rematerialized before the P-barrier, xlF only after V_r consumed xrF.
// Loops indexing sacc stay fully unrolled (runtime-indexed vectors -> scratch).

typedef __attribute__((ext_vector_type(8))) __bf16 bf16x8;
typedef __attribute__((ext_vector_type(4))) __bf16 bf16x4;
typedef __attribute__((ext_vector_type(4))) float f4;

#define MFMA(A, B, C) __builtin_amdgcn_mfma_f32_16x16x32_bf16((A), (B), (C), 0, 0, 0)
#define SCALE_QK 0.08838834764831845f  // 128^-0.5

// XOR-swizzled LDS offset for a [128][128] bf16 slot (256 B row stride).
static __device__ __forceinline__ int eoff(int n, int k) {
  return (n << 8) + ((((k >> 3) ^ (n & 7)) << 4) | ((k & 7) << 1));
}

// Prep: transpose 4 fp32 [k][n] weight matrices to bf16 [n][k] in workspace.
__global__ void prep_w(const float* __restrict__ w0, const float* __restrict__ w1,
                       const float* __restrict__ w2, const float* __restrict__ w3,
                       __bf16* __restrict__ out) {
  int m = blockIdx.y;
  const float* src = (m == 0) ? w0 : (m == 1) ? w1 : (m == 2) ? w2 : w3;
  int t = blockIdx.x * 256 + threadIdx.x;  // 0..16383
  int k = t >> 7, n = t & 127;
  out[m * 16384 + n * 128 + k] = (__bf16)src[k * 128 + n];
}

// LayerNorm of one row (A-frag layout: row = w*16+l16, k = ks*32+quad*8+0..7),
// row reduce = 2 shuffles (row shared by 4 quads). Emits ln(x) bf16 A-frags.
static __device__ __forceinline__ void ln_frags(const float* __restrict__ xp, size_t base,
                                                const float* __restrict__ g,
                                                const float* __restrict__ b, int row,
                                                int quad, bf16x8* lF) {
  float4 v[8];
#pragma unroll
  for (int t = 0; t < 8; ++t)
    v[t] = *(const float4*)(xp + base + row * 128 + (t >> 1) * 32 + quad * 8 + (t & 1) * 4);
  float s = 0.f, s2 = 0.f;
#pragma unroll
  for (int t = 0; t < 8; ++t) {
    s += v[t].x + v[t].y + v[t].z + v[t].w;
    s2 += v[t].x * v[t].x + v[t].y * v[t].y + v[t].z * v[t].z + v[t].w * v[t].w;
  }
  s += __shfl_xor(s, 16);
  s += __shfl_xor(s, 32);
  s2 += __shfl_xor(s2, 16);
  s2 += __shfl_xor(s2, 32);
  float mean = s * 0.0078125f;
  float var = s2 * 0.0078125f - mean * mean;
  float rstd = rsqrtf(var + 1e-6f);
#pragma unroll
  for (int ks = 0; ks < 4; ++ks) {
    bf16x8 lu;
#pragma unroll
    for (int t = 0; t < 2; ++t) {
      float4 q = v[ks * 2 + t];
      float4 gv = *(const float4*)(g + ks * 32 + quad * 8 + t * 4);
      float4 bv = *(const float4*)(b + ks * 32 + quad * 8 + t * 4);
      lu[t * 4 + 0] = (__bf16)((q.x - mean) * rstd * gv.x + bv.x);
      lu[t * 4 + 1] = (__bf16)((q.y - mean) * rstd * gv.y + bv.y);
      lu[t * 4 + 2] = (__bf16)((q.z - mean) * rstd * gv.z + bv.z);
      lu[t * 4 + 3] = (__bf16)((q.w - mean) * rstd * gv.w + bv.w);
    }
    lF[ks] = lu;
  }
}

// Raw x row -> bf16 A-frags (re-materialization read; x is L3-resident).
static __device__ __forceinline__ void x_frags(const float* __restrict__ xp, size_t base,
                                               int row, int quad, bf16x8* xF) {
#pragma unroll
  for (int ks = 0; ks < 4; ++ks) {
    bf16x8 xu;
#pragma unroll
    for (int t = 0; t < 2; ++t) {
      float4 q = *(const float4*)(xp + base + row * 128 + ks * 32 + quad * 8 + t * 4);
      xu[t * 4 + 0] = (__bf16)q.x;
      xu[t * 4 + 1] = (__bf16)q.y;
      xu[t * 4 + 2] = (__bf16)q.z;
      xu[t * 4 + 3] = (__bf16)q.w;
    }
    xF[ks] = xu;
  }
}

// Projection: out = A @ W + bias. A from registers, W B-fragments straight
// from global (bf16 [n][k], L1/L2-hot: 32 KB reused by all 1024 blocks).
// TRANSPOSED=0: row-major [i][c] into slot. TRANSPOSED=1: [c][i] (for V^T).
// unroll 2: max 8 in-flight weight loads (v3's full unroll hoisted 32 -> spill).
template <int TRANSPOSED>
static __device__ __forceinline__ void proj_g(const bf16x8* aF,
                                              const __bf16* __restrict__ wTm, char* dst,
                                              const float* __restrict__ bias, float scale,
                                              int w, int l16, int quad) {
#pragma unroll 2
  for (int nt = 0; nt < 8; ++nt) {
    f4 a = {0.f, 0.f, 0.f, 0.f};
    const __bf16* wrow = wTm + (nt * 16 + l16) * 128 + quad * 8;
#pragma unroll
    for (int ks = 0; ks < 4; ++ks) {
      bf16x8 bf = *(const bf16x8*)(wrow + ks * 32);
      a = MFMA(aF[ks], bf, a);
    }
    float bs = bias[nt * 16 + l16];
    if (TRANSPOSED) {
      int c = nt * 16 + l16;
      bf16x4 u;
#pragma unroll
      for (int r = 0; r < 4; ++r) u[r] = (__bf16)((a[r] + bs) * scale);
      *(bf16x4*)(dst + eoff(c, w * 16 + quad * 4)) = u;
    } else {
#pragma unroll
      for (int r = 0; r < 4; ++r) {
        int i = w * 16 + quad * 4 + r;
        *(__bf16*)(dst + eoff(i, nt * 16 + l16)) = (__bf16)((a[r] + bs) * scale);
      }
    }
  }
}

// f = P @ V fused with epilogue: out = x + scl[c] * f, straight to global.
// unroll 2 caps hoisted LDS/global loads.
static __device__ __forceinline__ void pv_epi(const bf16x8* pF, const char* vslot,
                                              const float* __restrict__ xp, size_t base,
                                              const float* __restrict__ scl,
                                              float* __restrict__ outp, int w, int l16,
                                              int quad) {
#pragma unroll 2
  for (int nt = 0; nt < 8; ++nt) {
    f4 a = {0.f, 0.f, 0.f, 0.f};
#pragma unroll
    for (int ks = 0; ks < 4; ++ks) {
      bf16x8 bf = *(const bf16x8*)(vslot + eoff(nt * 16 + l16, ks * 32 + quad * 8));
      a = MFMA(pF[ks], bf, a);
    }
    int c = nt * 16 + l16;
    float sv = scl[c];
#pragma unroll
    for (int r = 0; r < 4; ++r) {
      int i = w * 16 + quad * 4 + r;
      outp[base + i * 128 + c] = xp[base + i * 128 + c] + sv * (float)a[r];
    }
  }
}

__global__ __launch_bounds__(512, 4) void scam_fused(
    const float* __restrict__ xl, const float* __restrict__ xr,
    const float* __restrict__ gl, const float* __restrict__ bl,
    const float* __restrict__ gr, const float* __restrict__ br,
    const __bf16* __restrict__ wT,  // 4 x [128][128] bf16, order: ql, qr, vl, vr
    const float* __restrict__ bql, const float* __restrict__ bqr,
    const float* __restrict__ bvl, const float* __restrict__ bvr,
    const float* __restrict__ beta, const float* __restrict__ gamma,
    float* __restrict__ out0, float* __restrict__ out1) {
  __shared__ char S[73728];       // S1 32K | S2 32K | colred 8K
  char* S1 = S;
  char* S2 = S + 32768;
  float* colred0 = (float*)(S + 65536);  // 8 waves x 128 cols
  float* colred1 = (float*)(S + 69632);
  int tid = threadIdx.x;
  int lane = tid & 63, w = tid >> 6;  // wave w owns rows [16w, 16w+16)
  int quad = lane >> 4, l16 = lane & 15;
  int row = w * 16 + l16;
  size_t base = (size_t)blockIdx.x << 14;  // bh * 128*128

  // ---- Phase A/B: LN -> Q projection, one side at a time (staggered) ----
  {
    bf16x8 llF[4];
    ln_frags(xl, base, gl, bl, row, quad, llF);
    proj_g<0>(llF, wT, S1, bql, SCALE_QK, w, l16, quad);  // llF dies here
  }
  {
    bf16x8 lrF[4];
    ln_frags(xr, base, gr, br, row, quad, lrF);
    proj_g<0>(lrF, wT + 16384, S2, bqr, 1.0f, w, l16, quad);  // lrF dies here
  }
  __syncthreads();  // (1) q_l / q_r visible to all waves

  bf16x8 qlF[4];
#pragma unroll
  for (int ks = 0; ks < 4; ++ks)
    qlF[ks] = *(const bf16x8*)(S1 + eoff(row, ks * 32 + quad * 8));  // own band

  // ---- Phase D: S = q_l @ q_r^T (full unroll: sacc is register-indexed) ----
  f4 sacc[8];
#pragma unroll
  for (int nt = 0; nt < 8; ++nt) {
    f4 z = {0.f, 0.f, 0.f, 0.f};
    sacc[nt] = z;
  }
#pragma unroll
  for (int nt = 0; nt < 8; ++nt)
#pragma unroll
    for (int ks = 0; ks < 4; ++ks) {
      bf16x8 bf = *(const bf16x8*)(S2 + eoff(nt * 16 + l16, ks * 32 + quad * 8));
      sacc[nt] = MFMA(qlF[ks], bf, sacc[nt]);
    }

  // ---- Phase E: dual softmax stats ----
  float rm[4], rinv[4];
#pragma unroll
  for (int r = 0; r < 4; ++r) {
    float m = -1e30f;
#pragma unroll
    for (int nt = 0; nt < 8; ++nt) m = fmaxf(m, sacc[nt][r]);
#pragma unroll
    for (int d = 1; d < 16; d <<= 1) m = fmaxf(m, __shfl_xor(m, d));
    float s = 0.f;
#pragma unroll
    for (int nt = 0; nt < 8; ++nt) s += __expf(sacc[nt][r] - m);
#pragma unroll
    for (int d = 1; d < 16; d <<= 1) s += __shfl_xor(s, d);
    rm[r] = m;
    rinv[r] = 1.f / s;
  }
  float cm[8], cinv[8];
#pragma unroll
  for (int nt = 0; nt < 8; ++nt) {
    float m = fmaxf(fmaxf(sacc[nt][0], sacc[nt][1]), fmaxf(sacc[nt][2], sacc[nt][3]));
    m = fmaxf(m, __shfl_xor(m, 16));
    m = fmaxf(m, __shfl_xor(m, 32));
    cm[nt] = m;
  }
  if (quad == 0) {
#pragma unroll
    for (int nt = 0; nt < 8; ++nt) colred0[w * 128 + nt * 16 + l16] = cm[nt];
  }
  __syncthreads();  // (2) also orders: all waves are past Phase D reads
#pragma unroll
  for (int nt = 0; nt < 8; ++nt) {
    float m = cm[nt];
#pragma unroll
    for (int ww = 0; ww < 8; ++ww) m = fmaxf(m, colred0[ww * 128 + nt * 16 + l16]);
    cm[nt] = m;
  }
#pragma unroll
  for (int nt = 0; nt < 8; ++nt) {
    float s = __expf(sacc[nt][0] - cm[nt]) + __expf(sacc[nt][1] - cm[nt]) +
              __expf(sacc[nt][2] - cm[nt]) + __expf(sacc[nt][3] - cm[nt]);
    s += __shfl_xor(s, 16);
    s += __shfl_xor(s, 32);
    cinv[nt] = s;  // wave-local column sum
  }
  if (quad == 0) {
#pragma unroll
    for (int nt = 0; nt < 8; ++nt) colred1[w * 128 + nt * 16 + l16] = cinv[nt];
  }
  __syncthreads();  // (3)
#pragma unroll
  for (int nt = 0; nt < 8; ++nt) {
    float s = 0.f;
#pragma unroll
    for (int ww = 0; ww < 8; ++ww) s += colred1[ww * 128 + nt * 16 + l16];
    cinv[nt] = 1.f / s;
  }

  // ---- Phase F: P_r -> S1 (own band), P_c^T -> S2; sacc+stats die here ----
#pragma unroll
  for (int nt = 0; nt < 8; ++nt) {
    bf16x4 pc;
#pragma unroll
    for (int r = 0; r < 4; ++r) {
      float sv = sacc[nt][r];
      int i = w * 16 + quad * 4 + r;
      *(__bf16*)(S1 + eoff(i, nt * 16 + l16)) = (__bf16)(__expf(sv - rm[r]) * rinv[r]);
      pc[r] = (__bf16)(__expf(sv - cm[nt]) * cinv[nt]);
    }
    *(bf16x4*)(S2 + eoff(nt * 16 + l16, w * 16 + quad * 4)) = pc;
  }

  // Re-materialize only xr frags here (needed first); xl comes later.
  bf16x8 xrF[4];
  x_frags(xr, base, row, quad, xrF);
  __syncthreads();  // (4) P tiles visible

  bf16x8 prF[4], pcF[4];
#pragma unroll
  for (int ks = 0; ks < 4; ++ks) {
    prF[ks] = *(const bf16x8*)(S1 + eoff(row, ks * 32 + quad * 8));
    pcF[ks] = *(const bf16x8*)(S2 + eoff(row, ks * 32 + quad * 8));
  }
  __syncthreads();  // (5) all P loads done before V^T overwrites slots

  // ---- Phase G: V_r^T -> S1 (xrF dies), then xl remat, V_l^T -> S2 ----
  proj_g<1>(xrF, wT + 3 * 16384, S1, bvr, 1.0f, w, l16, quad);
  {
    bf16x8 xlF[4];
    x_frags(xl, base, row, quad, xlF);
    proj_g<1>(xlF, wT + 2 * 16384, S2, bvl, 1.0f, w, l16, quad);
  }
  __syncthreads();  // (6)

  // ---- Phase H: both PV matmuls fused with epilogues ----
  pv_epi(prF, S1, xl, base, beta, out0, w, l16, quad);
  pv_epi(pcF, S2, xr, base, gamma, out1, w, l16, quad);
}

extern "C" void kernel_launch(void* const* d_in, const int* in_sizes, int n_in,
                              void* d_out, int out_size, void* d_ws, size_t ws_size,
                              hipStream_t stream) {
  const float* xl = (const float*)d_in[0];
  const float* xr = (const float*)d_in[1];
  const float* gl = (const float*)d_in[2];
  const float* bl = (const float*)d_in[3];
  const float* gr = (const float*)d_in[4];
  const float* br = (const float*)d_in[5];
  const float* wql = (const float*)d_in[6];
  const float* bql = (const float*)d_in[7];
  const float* wqr = (const float*)d_in[8];
  const float* bqr = (const float*)d_in[9];
  const float* wvl = (const float*)d_in[10];
  const float* bvl = (const float*)d_in[11];
  const float* wvr = (const float*)d_in[12];
  const float* bvr = (const float*)d_in[13];
  const float* beta = (const float*)d_in[14];
  const float* gamma = (const float*)d_in[15];

  __bf16* wT = (__bf16*)d_ws;          // 4 * 16384 bf16 = 128 KB scratch
  float* out0 = (float*)d_out;         // [8,128,128,128] fp32
  float* out1 = out0 + (size_t)8 * 128 * 128 * 128;

  prep_w<<<dim3(64, 4), 256, 0, stream>>>(wql, wqr, wvl, wvr, wT);
  scam_fused<<<1024, 512, 0, stream>>>(xl, xr, gl, bl, gr, br, wT, bql, bqr, bvl, bvr,
                                       beta, gamma, out0, out1);
}

// Round 4
// 386.296 us; speedup vs baseline: 1.5062x; 1.0098x over previous
//
#include <hip/hip_runtime.h>

// SCAM fused kernel for MI355X (gfx950) — v5 "lifetime surgery" on v4.
// Structure: 1024 blocks (one per (b,h) slice), 8 waves x 16-row bands,
// two 32 KB LDS slots + 8 KB colred (72 KB -> 2 blocks/CU).
// v5 changes (register-pressure + barrier diet):
//  - P_r written right after row stats (rm/rinv die before col stats).
//  - Single-pass column stats: (local max, local sum) pairs, one colred
//    round-trip, combine with exp-rescale. Softmax barriers 3 -> 1.
//  - prF loaded early (own-wave LDS data, no barrier needed); pcF loaded
//    only after pv0 -> P-fragment peak 32 -> 16 regs.
//  - xlF rematerialized after V_r projection; latency hides under pv0.
// Peak live set ~75-100 regs incl. AGPRs -> fits the 128 cap of (512,4).

typedef __attribute__((ext_vector_type(8))) __bf16 bf16x8;
typedef __attribute__((ext_vector_type(4))) __bf16 bf16x4;
typedef __attribute__((ext_vector_type(4))) float f4;

#define MFMA(A, B, C) __builtin_amdgcn_mfma_f32_16x16x32_bf16((A), (B), (C), 0, 0, 0)
#define SCALE_QK 0.08838834764831845f  // 128^-0.5

// XOR-swizzled LDS offset for a [128][128] bf16 slot (256 B row stride).
static __device__ __forceinline__ int eoff(int n, int k) {
  return (n << 8) + ((((k >> 3) ^ (n & 7)) << 4) | ((k & 7) << 1));
}

// Prep: transpose 4 fp32 [k][n] weight matrices to bf16 [n][k] in workspace.
__global__ void prep_w(const float* __restrict__ w0, const float* __restrict__ w1,
                       const float* __restrict__ w2, const float* __restrict__ w3,
                       __bf16* __restrict__ out) {
  int m = blockIdx.y;
  const float* src = (m == 0) ? w0 : (m == 1) ? w1 : (m == 2) ? w2 : w3;
  int t = blockIdx.x * 256 + threadIdx.x;  // 0..16383
  int k = t >> 7, n = t & 127;
  out[m * 16384 + n * 128 + k] = (__bf16)src[k * 128 + n];
}

// LayerNorm of one row (A-frag layout: row = w*16+l16, k = ks*32+quad*8+0..7),
// row reduce = 2 shuffles (row shared by 4 quads). Emits ln(x) bf16 A-frags.
static __device__ __forceinline__ void ln_frags(const float* __restrict__ xp, size_t base,
                                                const float* __restrict__ g,
                                                const float* __restrict__ b, int row,
                                                int quad, bf16x8* lF) {
  float4 v[8];
#pragma unroll
  for (int t = 0; t < 8; ++t)
    v[t] = *(const float4*)(xp + base + row * 128 + (t >> 1) * 32 + quad * 8 + (t & 1) * 4);
  float s = 0.f, s2 = 0.f;
#pragma unroll
  for (int t = 0; t < 8; ++t) {
    s += v[t].x + v[t].y + v[t].z + v[t].w;
    s2 += v[t].x * v[t].x + v[t].y * v[t].y + v[t].z * v[t].z + v[t].w * v[t].w;
  }
  s += __shfl_xor(s, 16);
  s += __shfl_xor(s, 32);
  s2 += __shfl_xor(s2, 16);
  s2 += __shfl_xor(s2, 32);
  float mean = s * 0.0078125f;
  float var = s2 * 0.0078125f - mean * mean;
  float rstd = rsqrtf(var + 1e-6f);
#pragma unroll
  for (int ks = 0; ks < 4; ++ks) {
    bf16x8 lu;
#pragma unroll
    for (int t = 0; t < 2; ++t) {
      float4 q = v[ks * 2 + t];
      float4 gv = *(const float4*)(g + ks * 32 + quad * 8 + t * 4);
      float4 bv = *(const float4*)(b + ks * 32 + quad * 8 + t * 4);
      lu[t * 4 + 0] = (__bf16)((q.x - mean) * rstd * gv.x + bv.x);
      lu[t * 4 + 1] = (__bf16)((q.y - mean) * rstd * gv.y + bv.y);
      lu[t * 4 + 2] = (__bf16)((q.z - mean) * rstd * gv.z + bv.z);
      lu[t * 4 + 3] = (__bf16)((q.w - mean) * rstd * gv.w + bv.w);
    }
    lF[ks] = lu;
  }
}

// Raw x row -> bf16 A-frags (re-materialization read; x is L2/L3-warm).
static __device__ __forceinline__ void x_frags(const float* __restrict__ xp, size_t base,
                                               int row, int quad, bf16x8* xF) {
#pragma unroll
  for (int ks = 0; ks < 4; ++ks) {
    bf16x8 xu;
#pragma unroll
    for (int t = 0; t < 2; ++t) {
      float4 q = *(const float4*)(xp + base + row * 128 + ks * 32 + quad * 8 + t * 4);
      xu[t * 4 + 0] = (__bf16)q.x;
      xu[t * 4 + 1] = (__bf16)q.y;
      xu[t * 4 + 2] = (__bf16)q.z;
      xu[t * 4 + 3] = (__bf16)q.w;
    }
    xF[ks] = xu;
  }
}

// Projection: out = A @ W + bias. A from registers, W B-fragments straight
// from global (bf16 [n][k], L1/L2-hot: 32 KB reused by all 1024 blocks).
// TRANSPOSED=0: row-major [i][c] into slot. TRANSPOSED=1: [c][i] (for V^T).
// unroll 2 caps in-flight weight loads at 8 (full unroll hoisted 32 -> spill).
template <int TRANSPOSED>
static __device__ __forceinline__ void proj_g(const bf16x8* aF,
                                              const __bf16* __restrict__ wTm, char* dst,
                                              const float* __restrict__ bias, float scale,
                                              int w, int l16, int quad) {
#pragma unroll 2
  for (int nt = 0; nt < 8; ++nt) {
    f4 a = {0.f, 0.f, 0.f, 0.f};
    const __bf16* wrow = wTm + (nt * 16 + l16) * 128 + quad * 8;
#pragma unroll
    for (int ks = 0; ks < 4; ++ks) {
      bf16x8 bf = *(const bf16x8*)(wrow + ks * 32);
      a = MFMA(aF[ks], bf, a);
    }
    float bs = bias[nt * 16 + l16];
    if (TRANSPOSED) {
      int c = nt * 16 + l16;
      bf16x4 u;
#pragma unroll
      for (int r = 0; r < 4; ++r) u[r] = (__bf16)((a[r] + bs) * scale);
      *(bf16x4*)(dst + eoff(c, w * 16 + quad * 4)) = u;
    } else {
#pragma unroll
      for (int r = 0; r < 4; ++r) {
        int i = w * 16 + quad * 4 + r;
        *(__bf16*)(dst + eoff(i, nt * 16 + l16)) = (__bf16)((a[r] + bs) * scale);
      }
    }
  }
}

// f = P @ V fused with epilogue: out = x + scl[c] * f, straight to global.
static __device__ __forceinline__ void pv_epi(const bf16x8* pF, const char* vslot,
                                              const float* __restrict__ xp, size_t base,
                                              const float* __restrict__ scl,
                                              float* __restrict__ outp, int w, int l16,
                                              int quad) {
#pragma unroll 2
  for (int nt = 0; nt < 8; ++nt) {
    f4 a = {0.f, 0.f, 0.f, 0.f};
#pragma unroll
    for (int ks = 0; ks < 4; ++ks) {
      bf16x8 bf = *(const bf16x8*)(vslot + eoff(nt * 16 + l16, ks * 32 + quad * 8));
      a = MFMA(pF[ks], bf, a);
    }
    int c = nt * 16 + l16;
    float sv = scl[c];
#pragma unroll
    for (int r = 0; r < 4; ++r) {
      int i = w * 16 + quad * 4 + r;
      outp[base + i * 128 + c] = xp[base + i * 128 + c] + sv * (float)a[r];
    }
  }
}

__global__ __launch_bounds__(512, 4) void scam_fused(
    const float* __restrict__ xl, const float* __restrict__ xr,
    const float* __restrict__ gl, const float* __restrict__ bl,
    const float* __restrict__ gr, const float* __restrict__ br,
    const __bf16* __restrict__ wT,  // 4 x [128][128] bf16, order: ql, qr, vl, vr
    const float* __restrict__ bql, const float* __restrict__ bqr,
    const float* __restrict__ bvl, const float* __restrict__ bvr,
    const float* __restrict__ beta, const float* __restrict__ gamma,
    float* __restrict__ out0, float* __restrict__ out1) {
  __shared__ char S[73728];       // S1 32K | S2 32K | colred 8K
  char* S1 = S;
  char* S2 = S + 32768;
  float* colred0 = (float*)(S + 65536);  // 8 waves x 128 cols: local max
  float* colred1 = (float*)(S + 69632);  // 8 waves x 128 cols: local sum
  int tid = threadIdx.x;
  int lane = tid & 63, w = tid >> 6;  // wave w owns rows [16w, 16w+16)
  int quad = lane >> 4, l16 = lane & 15;
  int row = w * 16 + l16;
  size_t base = (size_t)blockIdx.x << 14;  // bh * 128*128

  // ---- Phase A/B: LN -> Q projection, one side at a time (staggered) ----
  {
    bf16x8 llF[4];
    ln_frags(xl, base, gl, bl, row, quad, llF);
    proj_g<0>(llF, wT, S1, bql, SCALE_QK, w, l16, quad);  // llF dies here
  }
  {
    bf16x8 lrF[4];
    ln_frags(xr, base, gr, br, row, quad, lrF);
    proj_g<0>(lrF, wT + 16384, S2, bqr, 1.0f, w, l16, quad);  // lrF dies here
  }
  __syncthreads();  // (1) q_l / q_r visible to all waves

  bf16x8 qlF[4];
#pragma unroll
  for (int ks = 0; ks < 4; ++ks)
    qlF[ks] = *(const bf16x8*)(S1 + eoff(row, ks * 32 + quad * 8));  // own band

  // ---- Phase D: S = q_l @ q_r^T (full unroll: sacc is register-indexed) ----
  f4 sacc[8];
#pragma unroll
  for (int nt = 0; nt < 8; ++nt) {
    f4 z = {0.f, 0.f, 0.f, 0.f};
    sacc[nt] = z;
  }
#pragma unroll
  for (int nt = 0; nt < 8; ++nt)
#pragma unroll
    for (int ks = 0; ks < 4; ++ks) {
      bf16x8 bf = *(const bf16x8*)(S2 + eoff(nt * 16 + l16, ks * 32 + quad * 8));
      sacc[nt] = MFMA(qlF[ks], bf, sacc[nt]);
    }

  // ---- Phase E1: row stats + immediate P_r write (rm/rinv die here) ----
  // Legal without barrier: wave w's P_r band overwrites only S1 rows that
  // wave w itself read for qlF (within-wave LDS ordering).
  {
    float rm[4], rinv[4];
#pragma unroll
    for (int r = 0; r < 4; ++r) {
      float m = -1e30f;
#pragma unroll
      for (int nt = 0; nt < 8; ++nt) m = fmaxf(m, sacc[nt][r]);
#pragma unroll
      for (int d = 1; d < 16; d <<= 1) m = fmaxf(m, __shfl_xor(m, d));
      float s = 0.f;
#pragma unroll
      for (int nt = 0; nt < 8; ++nt) s += __expf(sacc[nt][r] - m);
#pragma unroll
      for (int d = 1; d < 16; d <<= 1) s += __shfl_xor(s, d);
      rm[r] = m;
      rinv[r] = 1.f / s;
    }
#pragma unroll
    for (int nt = 0; nt < 8; ++nt) {
#pragma unroll
      for (int r = 0; r < 4; ++r) {
        int i = w * 16 + quad * 4 + r;
        *(__bf16*)(S1 + eoff(i, nt * 16 + l16)) =
            (__bf16)(__expf(sacc[nt][r] - rm[r]) * rinv[r]);
      }
    }
  }

  // Re-materialize xr frags (latency hides under col stats + barrier).
  bf16x8 xrF[4];
  x_frags(xr, base, row, quad, xrF);

  // ---- Phase E2: column stats, single pass (local max + local sum) ----
  float cm[8], cinv[8];
#pragma unroll
  for (int nt = 0; nt < 8; ++nt) {
    float m = fmaxf(fmaxf(sacc[nt][0], sacc[nt][1]), fmaxf(sacc[nt][2], sacc[nt][3]));
    m = fmaxf(m, __shfl_xor(m, 16));
    m = fmaxf(m, __shfl_xor(m, 32));
    float s = __expf(sacc[nt][0] - m) + __expf(sacc[nt][1] - m) +
              __expf(sacc[nt][2] - m) + __expf(sacc[nt][3] - m);
    s += __shfl_xor(s, 16);
    s += __shfl_xor(s, 32);
    cm[nt] = m;
    cinv[nt] = s;  // wave-local sum (temporarily)
  }
  if (quad == 0) {
#pragma unroll
    for (int nt = 0; nt < 8; ++nt) {
      colred0[w * 128 + nt * 16 + l16] = cm[nt];
      colred1[w * 128 + nt * 16 + l16] = cinv[nt];
    }
  }
  __syncthreads();  // (2) colred visible; also: all waves past QK's S2 reads
#pragma unroll
  for (int nt = 0; nt < 8; ++nt) {
    float m = -1e30f;
#pragma unroll
    for (int ww = 0; ww < 8; ++ww) m = fmaxf(m, colred0[ww * 128 + nt * 16 + l16]);
    float s = 0.f;
#pragma unroll
    for (int ww = 0; ww < 8; ++ww)
      s += colred1[ww * 128 + nt * 16 + l16] *
           __expf(colred0[ww * 128 + nt * 16 + l16] - m);
    cm[nt] = m;
    cinv[nt] = 1.f / s;
  }

  // ---- Phase F: P_c^T -> S2 (sacc, cm, cinv die here) ----
#pragma unroll
  for (int nt = 0; nt < 8; ++nt) {
    bf16x4 pc;
#pragma unroll
    for (int r = 0; r < 4; ++r)
      pc[r] = (__bf16)(__expf(sacc[nt][r] - cm[nt]) * cinv[nt]);
    *(bf16x4*)(S2 + eoff(nt * 16 + l16, w * 16 + quad * 4)) = pc;
  }

  // prF: own-wave P_r band, no barrier needed (within-wave LDS ordering).
  bf16x8 prF[4];
#pragma unroll
  for (int ks = 0; ks < 4; ++ks)
    prF[ks] = *(const bf16x8*)(S1 + eoff(row, ks * 32 + quad * 8));
  __syncthreads();  // (3) P_c^T writes done; all prF reads done -> S1 free

  // ---- Phase G1: V_r^T -> S1 (xrF dies); issue xl remat under the barrier --
  proj_g<1>(xrF, wT + 3 * 16384, S1, bvr, 1.0f, w, l16, quad);
  bf16x8 xlF[4];
  x_frags(xl, base, row, quad, xlF);
  __syncthreads();  // (4) V_r ready

  // ---- Phase H1: f_r2l = P_r @ V_r fused epilogue -> out0 (prF dies) ----
  pv_epi(prF, S1, xl, base, beta, out0, w, l16, quad);

  // pcF: cross-wave columns, but barrier (3) already ordered the writes.
  bf16x8 pcF[4];
#pragma unroll
  for (int ks = 0; ks < 4; ++ks)
    pcF[ks] = *(const bf16x8*)(S2 + eoff(row, ks * 32 + quad * 8));
  __syncthreads();  // (5) all S2 reads + all pv0 S1 reads done

  // ---- Phase G2: V_l^T -> S2 (xlF dies) ----
  proj_g<1>(xlF, wT + 2 * 16384, S2, bvl, 1.0f, w, l16, quad);
  __syncthreads();  // (6) V_l ready

  // ---- Phase H2: f_l2r = P_c @ V_l fused epilogue -> out1 ----
  pv_epi(pcF, S2, xr, base, gamma, out1, w, l16, quad);
}

extern "C" void kernel_launch(void* const* d_in, const int* in_sizes, int n_in,
                              void* d_out, int out_size, void* d_ws, size_t ws_size,
                              hipStream_t stream) {
  const float* xl = (const float*)d_in[0];
  const float* xr = (const float*)d_in[1];
  const float* gl = (const float*)d_in[2];
  const float* bl = (const float*)d_in[3];
  const float* gr = (const float*)d_in[4];
  const float* br = (const float*)d_in[5];
  const float* wql = (const float*)d_in[6];
  const float* bql = (const float*)d_in[7];
  const float* wqr = (const float*)d_in[8];
  const float* bqr = (const float*)d_in[9];
  const float* wvl = (const float*)d_in[10];
  const float* bvl = (const float*)d_in[11];
  const float* wvr = (const float*)d_in[12];
  const float* bvr = (const float*)d_in[13];
  const float* beta = (const float*)d_in[14];
  const float* gamma = (const float*)d_in[15];

  __bf16* wT = (__bf16*)d_ws;          // 4 * 16384 bf16 = 128 KB scratch
  float* out0 = (float*)d_out;         // [8,128,128,128] fp32
  float* out1 = out0 + (size_t)8 * 128 * 128 * 128;

  prep_w<<<dim3(64, 4), 256, 0, stream>>>(wql, wqr, wvl, wvr, wT);
  scam_fused<<<1024, 512, 0, stream>>>(xl, xr, gl, bl, gr, br, wT, bql, bqr, bvl, bvr,
                                       beta, gamma, out0, out1);
}